// Round 9
// baseline (579.314 us; speedup 1.0000x reference)
//
#include <hip/hip_runtime.h>
#include <stdint.h>

#define Tdim 128
#define Zdim 100
#define Sdim 6
#define Hdim 64
#define ZB   3200           // Z*B
#define F1   512
#define F2   128
#define Mrows (ZB * Tdim)   // 409600

typedef _Float16 f16x8 __attribute__((ext_vector_type(8)));
typedef _Float16 f16x4 __attribute__((ext_vector_type(4)));
typedef float f32x4 __attribute__((ext_vector_type(4)));
typedef uint32_t u32x4 __attribute__((ext_vector_type(4)));

__device__ __forceinline__ float sigmoidf_fast(float x) {
  return 1.f / (1.f + __expf(-x));
}
__device__ __forceinline__ float tanhf_fast(float x) {
  return 1.f - 2.f / (__expf(2.f * x) + 1.f);
}

// ---------------------------------------------------------------- prep
// Wf[192][96] fp16: [W_hh | W_ih | 0] per gate (K=96 fused), for the GRU.
// w1p frag-linear: [kt][ntl][kfrag][lane][8].  32768 f16.
// w2p frag-linear: [kt][nt][lane][8].          65536 f16.
__global__ __launch_bounds__(256) void prep_kernel(
    const float* __restrict__ W_ih, const float* __restrict__ W_hh,
    const float* __restrict__ w1, const float* __restrict__ w2,
    _Float16* __restrict__ Wf, _Float16* __restrict__ w1p,
    _Float16* __restrict__ w2p) {
  int i = blockIdx.x * 256 + threadIdx.x;     // grid covers 116736
  if (i < 192 * 96) {
    int g = i / 96, k = i - g * 96;
    float v = (k < 64) ? W_hh[g * 64 + k] : ((k < 70) ? W_ih[g * 6 + (k - 64)] : 0.f);
    Wf[i] = (_Float16)v;
  }
  int j = i - 192 * 96;
  if (j >= 0 && j < 32768) {
    int kt = j >> 11, ntl = (j >> 10) & 1, kf = (j >> 9) & 1;
    int lane = (j >> 3) & 63, e = j & 7;
    int q = lane >> 4, c = lane & 15;
    int row = kt * 32 + ntl * 16 + c;
    int h = kf * 32 + q * 8 + e;
    w1p[j] = (_Float16)w1[row * 64 + h];
  }
  int l = j - 32768;
  if (l >= 0 && l < 65536) {
    int kt = l >> 12, nt = (l >> 9) & 7;
    int lane = (l >> 3) & 63, e = l & 7;
    int q = lane >> 4, c = lane & 15;
    int row = nt * 16 + c;
    int k = kt * 32 + q * 8 + e;
    w2p[l] = (_Float16)w2[row * 512 + k];
  }
}

// ---------------------------------------------------------------- GRU via MFMA
// Block = 4 waves, 16 rows; wave w owns gate-dims [16w,16w+16) of r,z,n.
// Per-step h-MFMAs are INDEPENDENT partials (Bh0 and Bh1 halves summed with
// v_add) — one MFMA dep level on the serial path instead of two. x-projection
// for t+1 pipelined pre-barrier. Loop globally silent; burst dumps per chunk.
__global__ __launch_bounds__(256, 1) void gru_kernel(
    const float* __restrict__ x, const _Float16* __restrict__ Wf,
    const float* __restrict__ b_ih, const float* __restrict__ b_hh,
    _Float16* __restrict__ sx) {
  __shared__ __align__(16) _Float16 hist[32][16][72];  // 72 KB
  __shared__ __align__(16) _Float16 xs[Tdim][16][8];   // 32 KB
  const int tid = threadIdx.x;
  const int lane = tid & 63;
  const int w = tid >> 6;                     // wave id 0..3
  const int c = lane & 15;                    // MFMA col = row index
  const int q = lane >> 4;                    // quad

  // ---- preload x for this block's 16 rows, pre-converted to fp16
  for (int i = 0; i < 8; i++) {
    int idx = i * 256 + tid;                  // 0..2047 = (t, row)
    int t = idx >> 4, row = idx & 15;
    int nr = blockIdx.x * 16 + row;           // n = z*32 + b
    const float* p = x + (size_t)(nr & 31) * (Tdim * Zdim * Sdim)
                       + (size_t)t * (Zdim * Sdim) + (size_t)(nr >> 5) * Sdim;
    f16x8 v;
    v[0] = (_Float16)p[0]; v[1] = (_Float16)p[1]; v[2] = (_Float16)p[2];
    v[3] = (_Float16)p[3]; v[4] = (_Float16)p[4]; v[5] = (_Float16)p[5];
    v[6] = (_Float16)0.f;  v[7] = (_Float16)0.f;
    *(f16x8*)&xs[t][row][0] = v;
  }

  const int gr0 = w * 16;                     // r-gate tile base
  const int gz0 = 64 + w * 16;                // z-gate tile base
  const int gn0 = 128 + w * 16;               // n-gate tile base

  // A-frags: A[m=c][k=q*8+j] per 16-gate tile, K=96 fused [h|x|0]
  f16x8 Ar[3], Az[3], Anh[2], Ani;
#pragma unroll
  for (int kf = 0; kf < 3; kf++) {
    Ar[kf] = *(const f16x8*)(Wf + (size_t)(gr0 + c) * 96 + kf * 32 + q * 8);
    Az[kf] = *(const f16x8*)(Wf + (size_t)(gz0 + c) * 96 + kf * 32 + q * 8);
  }
  Anh[0] = *(const f16x8*)(Wf + (size_t)(gn0 + c) * 96 + q * 8);
  Anh[1] = *(const f16x8*)(Wf + (size_t)(gn0 + c) * 96 + 32 + q * 8);
  Ani    = *(const f16x8*)(Wf + (size_t)(gn0 + c) * 96 + 64 + q * 8);

  // biases in D-layout (gate-local m = q*4 + r)
  f32x4 Cr, Cz, Cnh, Cni;
  {
    f32x4 bir = *(const f32x4*)(b_ih + gr0 + q * 4);
    f32x4 bhr = *(const f32x4*)(b_hh + gr0 + q * 4);
    f32x4 biz = *(const f32x4*)(b_ih + gz0 + q * 4);
    f32x4 bhz = *(const f32x4*)(b_hh + gz0 + q * 4);
#pragma unroll
    for (int r = 0; r < 4; r++) { Cr[r] = bir[r] + bhr[r]; Cz[r] = biz[r] + bhz[r]; }
    Cnh = *(const f32x4*)(b_hh + gn0 + q * 4);
    Cni = *(const f32x4*)(b_ih + gn0 + q * 4);
  }

  __syncthreads();                            // xs ready

  f16x8 Bh0 = {0, 0, 0, 0, 0, 0, 0, 0};
  f16x8 Bh1 = {0, 0, 0, 0, 0, 0, 0, 0};
  f32x4 hprev = {0.f, 0.f, 0.f, 0.f};
  const f32x4 zero4 = {0.f, 0.f, 0.f, 0.f};

  // ---- pipeline seeds for t=0: x-projection MFMAs
  f32x4 Dr_s, Dz_s, Dni_s;
  {
    f16x8 xv8 = *(const f16x8*)&xs[0][c][0];
    f16x8 Bx;
#pragma unroll
    for (int j = 0; j < 8; j++) Bx[j] = (q == 0) ? xv8[j] : (_Float16)0.f;
    Dni_s = __builtin_amdgcn_mfma_f32_16x16x32_f16(Ani, Bx, Cni, 0, 0, 0);
    Dr_s  = __builtin_amdgcn_mfma_f32_16x16x32_f16(Ar[2], Bx, Cr, 0, 0, 0);
    Dz_s  = __builtin_amdgcn_mfma_f32_16x16x32_f16(Az[2], Bx, Cz, 0, 0, 0);
  }

#pragma unroll 1
  for (int tch = 0; tch < 4; tch++) {
#pragma unroll 1
    for (int tc = 0; tc < 32; tc++) {
      const int t = tch * 32 + tc;
      // ---- h-dependent MFMAs: 6 INDEPENDENT partials, one dep level
      f32x4 Dnh0 = __builtin_amdgcn_mfma_f32_16x16x32_f16(Anh[0], Bh0, Cnh, 0, 0, 0);
      f32x4 Dr0  = __builtin_amdgcn_mfma_f32_16x16x32_f16(Ar[0], Bh0, Dr_s, 0, 0, 0);
      f32x4 Dz0  = __builtin_amdgcn_mfma_f32_16x16x32_f16(Az[0], Bh0, Dz_s, 0, 0, 0);
      f32x4 Dnh1 = __builtin_amdgcn_mfma_f32_16x16x32_f16(Anh[1], Bh1, zero4, 0, 0, 0);
      f32x4 Dr1  = __builtin_amdgcn_mfma_f32_16x16x32_f16(Ar[1], Bh1, zero4, 0, 0, 0);
      f32x4 Dz1  = __builtin_amdgcn_mfma_f32_16x16x32_f16(Az[1], Bh1, zero4, 0, 0, 0);

      f16x4 pk;
#pragma unroll
      for (int r = 0; r < 4; r++) {
        float rr = sigmoidf_fast(Dr0[r] + Dr1[r]);
        float zg = sigmoidf_fast(Dz0[r] + Dz1[r]);
        float nn = tanhf_fast(Dni_s[r] + rr * (Dnh0[r] + Dnh1[r]));
        float hnew = nn + zg * (hprev[r] - nn);
        hprev[r] = hnew;
        pk[r] = (_Float16)hnew;
      }
      *(f16x4*)&hist[tc][c][w * 16 + q * 4] = pk;

      // ---- pre-barrier: x-projection for t+1 (h-independent, hides behind skew)
      if (t + 1 < Tdim) {
        f16x8 xv8 = *(const f16x8*)&xs[t + 1][c][0];
        f16x8 Bx;
#pragma unroll
        for (int j = 0; j < 8; j++) Bx[j] = (q == 0) ? xv8[j] : (_Float16)0.f;
        Dni_s = __builtin_amdgcn_mfma_f32_16x16x32_f16(Ani, Bx, Cni, 0, 0, 0);
        Dr_s  = __builtin_amdgcn_mfma_f32_16x16x32_f16(Ar[2], Bx, Cr, 0, 0, 0);
        Dz_s  = __builtin_amdgcn_mfma_f32_16x16x32_f16(Az[2], Bx, Cz, 0, 0, 0);
      }
      __syncthreads();                        // lgkm-only drain
      Bh0 = *(const f16x8*)&hist[tc][c][q * 8];
      Bh1 = *(const f16x8*)&hist[tc][c][32 + q * 8];
    }
    // coalesced dump of the 32-step chunk; wave w handles rows 4w..4w+3
    {
      const int t0 = tch * 32;
#pragma unroll
      for (int rr2 = 0; rr2 < 4; rr2++) {
        const int row = w * 4 + rr2;
        const int nrow = blockIdx.x * 16 + row;
        _Float16* dst = sx + (size_t)nrow * Tdim * Hdim + (size_t)t0 * Hdim;
#pragma unroll
        for (int it = 0; it < 4; it++) {
          int idx = it * 64 + lane;           // 0..255
          int tcc = idx >> 3, hd8 = idx & 7;
          f16x8 vv = *(const f16x8*)&hist[tcc][row][hd8 * 8];
          *(f16x8*)(dst + tcc * 64 + hd8 * 8) = vv;  // lane-contiguous 1 KB/iter
        }
      }
      __syncthreads();                        // dump reads done before hist reuse
    }
  }
}

// ---------------------------------------------------------------- fused MLP
// Block = 4 waves / 256 rows; wave = 64 rows (4 groups of 16) so every
// LDS A-frag read feeds 4 MFMAs. Weights double-buffered; rep single-buffered
// (wave-private, in-order). b1 seeded into MFMA C. 40 KB LDS.
// VGPR_Count measured 120 -> (256,3) fits (cap 170): 3 blocks/CU.
__global__ __launch_bounds__(256, 3) void mlp_kernel(
    const _Float16* __restrict__ sx, const _Float16* __restrict__ w1p,
    const _Float16* __restrict__ w2p, const float* __restrict__ b1,
    const float* __restrict__ b2, const float* __restrict__ w3,
    const float* __restrict__ b3, float* __restrict__ out) {
  __shared__ __align__(16) _Float16 w1s[2][2048];      // 8 KB  [ntl][kf][lane][8]
  __shared__ __align__(16) _Float16 w2s[2][4096];      // 16 KB [nt][lane][8]
  __shared__ __align__(16) _Float16 rep[4][4][512];    // 16 KB [wave][g][lane*8]
  const int tid = threadIdx.x;
  const int lane = tid & 63;
  const int wave = tid >> 6;
  const int c = lane & 15;
  const int q = lane >> 4;
  const size_t m0 = ((size_t)blockIdx.x * 4 + wave) * 64;

  // activations (rows) as B-frags for the whole kernel: 4 groups of 16 rows
  f16x8 Bs[4][2];
#pragma unroll
  for (int g = 0; g < 4; g++)
#pragma unroll
    for (int kk = 0; kk < 2; kk++)
      Bs[g][kk] = *(const f16x8*)(sx + (m0 + g * 16 + c) * Hdim + kk * 32 + q * 8);

  f32x4 acc2[4][8];
#pragma unroll
  for (int g = 0; g < 4; g++)
#pragma unroll
    for (int nt = 0; nt < 8; nt++) acc2[g][nt] = (f32x4){0.f, 0.f, 0.f, 0.f};

  u32x4 r1, r2a, r2b;
  // stage kt=0 and commit before the loop
  {
    const u32x4* g1 = (const u32x4*)(w1p);
    const u32x4* g2 = (const u32x4*)(w2p);
    r1 = g1[tid];
    r2a = g2[tid];
    r2b = g2[256 + tid];
    ((u32x4*)&w1s[0][0])[tid] = r1;
    ((u32x4*)&w2s[0][0])[tid] = r2a;
    ((u32x4*)&w2s[0][0])[256 + tid] = r2b;
  }
  __syncthreads();

#pragma unroll 1
  for (int kt = 0; kt < 16; kt++) {
    const int buf = kt & 1;
    // issue loads for kt+1 (land during compute below)
    if (kt + 1 < 16) {
      const u32x4* g1 = (const u32x4*)(w1p + (size_t)(kt + 1) * 2048);
      const u32x4* g2 = (const u32x4*)(w2p + (size_t)(kt + 1) * 4096);
      r1 = g1[tid];
      r2a = g2[tid];
      r2b = g2[256 + tid];
    }

    // ---- layer1: two 16-wide f1 tiles; A-frags at lane*16B (conflict-free)
#pragma unroll
    for (int ntl = 0; ntl < 2; ntl++) {
      const int f1b = kt * 32 + ntl * 16;
      f16x8 A0 = *(const f16x8*)&w1s[buf][ntl * 1024 + lane * 8];
      f16x8 A1 = *(const f16x8*)&w1s[buf][ntl * 1024 + 512 + lane * 8];
      f32x4 bb = *(const f32x4*)(b1 + f1b + q * 4);
      // write target: B-frag-linear — lane_b = (2*ntl + q/2)*16 + c, half q&1
      const int roff = ((2 * ntl + (q >> 1)) * 16 + c) * 8 + (q & 1) * 4;
#pragma unroll
      for (int g = 0; g < 4; g++) {
        f32x4 cc = __builtin_amdgcn_mfma_f32_16x16x32_f16(A0, Bs[g][0], bb, 0, 0, 0);
        cc = __builtin_amdgcn_mfma_f32_16x16x32_f16(A1, Bs[g][1], cc, 0, 0, 0);
        f16x4 pk;
#pragma unroll
        for (int r = 0; r < 4; r++)
          pk[r] = (_Float16)(cc[r] > 0.f ? cc[r] : 0.f);
        *(f16x4*)&rep[wave][g][roff] = pk;
      }
    }
    // ---- a1 chunk back as B-frags: direct lane-linear b128 (conflict-free)
    f16x8 Ba[4];
#pragma unroll
    for (int g = 0; g < 4; g++)
      Ba[g] = *(const f16x8*)&rep[wave][g][lane * 8];
    // ---- layer2 partial; A2 frags at lane*16B, each feeds 4 MFMAs
#pragma unroll
    for (int nt = 0; nt < 8; nt++) {
      f16x8 A2 = *(const f16x8*)&w2s[buf][nt * 512 + lane * 8];
#pragma unroll
      for (int g = 0; g < 4; g++)
        acc2[g][nt] = __builtin_amdgcn_mfma_f32_16x16x32_f16(A2, Ba[g], acc2[g][nt], 0, 0, 0);
    }

    // ---- commit kt+1 regs -> other LDS buf, then barrier
    if (kt + 1 < 16) {
      ((u32x4*)&w1s[buf ^ 1][0])[tid] = r1;
      ((u32x4*)&w2s[buf ^ 1][0])[tid] = r2a;
      ((u32x4*)&w2s[buf ^ 1][0])[256 + tid] = r2b;
      __syncthreads();
    }
  }

  // ---- layer3: out[row] = sum relu(a2 + b2) * w3 + b3
  float part[4] = {0.f, 0.f, 0.f, 0.f};
#pragma unroll
  for (int nt = 0; nt < 8; nt++) {
    f32x4 bb = *(const f32x4*)(b2 + nt * 16 + q * 4);
    f32x4 ww = *(const f32x4*)(w3 + nt * 16 + q * 4);
#pragma unroll
    for (int g = 0; g < 4; g++) {
#pragma unroll
      for (int r = 0; r < 4; r++) {
        float v = acc2[g][nt][r] + bb[r];
        v = v > 0.f ? v : 0.f;
        part[g] = fmaf(v, ww[r], part[g]);
      }
    }
  }
#pragma unroll
  for (int g = 0; g < 4; g++) {
    part[g] += __shfl_xor(part[g], 16, 64);
    part[g] += __shfl_xor(part[g], 32, 64);
  }
  // lane (c,q) writes row q*16+c of this wave's 64 rows
  float pv = (q == 0) ? part[0] : (q == 1) ? part[1] : (q == 2) ? part[2] : part[3];
  out[m0 + q * 16 + c] = pv + b3[0];
}

// ----------------------------------------------------------------
extern "C" void kernel_launch(void* const* d_in, const int* in_sizes, int n_in,
                              void* d_out, int out_size, void* d_ws, size_t ws_size,
                              hipStream_t stream) {
  const float* x    = (const float*)d_in[0];
  const float* W_ih = (const float*)d_in[1];
  const float* W_hh = (const float*)d_in[2];
  const float* b_ih = (const float*)d_in[3];
  const float* b_hh = (const float*)d_in[4];
  const float* w1   = (const float*)d_in[5];
  const float* b1   = (const float*)d_in[6];
  const float* w2   = (const float*)d_in[7];
  const float* b2   = (const float*)d_in[8];
  const float* w3   = (const float*)d_in[9];
  const float* b3   = (const float*)d_in[10];
  float* out = (float*)d_out;

  char* ws = (char*)d_ws;
  _Float16* sxf = (_Float16*)ws;                          // 52,428,800 B
  _Float16* Wf  = (_Float16*)(ws + 52428800);             // 36,864 B
  _Float16* w1p = (_Float16*)(ws + 52428800 + 36864);     // 65,536 B
  _Float16* w2p = (_Float16*)(ws + 52428800 + 36864 + 65536); // 131,072 B

  hipLaunchKernelGGL(prep_kernel, dim3(456), dim3(256), 0, stream,
                     W_ih, W_hh, w1, w2, Wf, w1p, w2p);
  hipLaunchKernelGGL(gru_kernel, dim3(ZB / 16), dim3(256), 0, stream,
                     x, Wf, b_ih, b_hh, sxf);
  hipLaunchKernelGGL(mlp_kernel, dim3(Mrows / 256), dim3(256), 0, stream,
                     sxf, w1p, w2p, b1, b2, w3, b3, out);
}

// Round 10
// 350.836 us; speedup vs baseline: 1.6512x; 1.6512x over previous
//
#include <hip/hip_runtime.h>
#include <stdint.h>

#define Tdim 128
#define Zdim 100
#define Sdim 6
#define Hdim 64
#define ZB   3200           // Z*B
#define F1   512
#define F2   128
#define Mrows (ZB * Tdim)   // 409600

typedef _Float16 f16x8 __attribute__((ext_vector_type(8)));
typedef _Float16 f16x4 __attribute__((ext_vector_type(4)));
typedef float f32x4 __attribute__((ext_vector_type(4)));
typedef uint32_t u32x4 __attribute__((ext_vector_type(4)));

__device__ __forceinline__ float sigmoidf_fast(float x) {
  return 1.f / (1.f + __expf(-x));
}
__device__ __forceinline__ float tanhf_fast(float x) {
  return 1.f - 2.f / (__expf(2.f * x) + 1.f);
}

// ---------------------------------------------------------------- prep
// Wf[192][96] fp16: [W_hh | W_ih | 0] per gate (K=96 fused), for the GRU.
// w1p frag-linear: [kt][ntl][kfrag][lane][8].  32768 f16.
// w2p frag-linear: [kt][nt][lane][8].          65536 f16.
__global__ __launch_bounds__(256) void prep_kernel(
    const float* __restrict__ W_ih, const float* __restrict__ W_hh,
    const float* __restrict__ w1, const float* __restrict__ w2,
    _Float16* __restrict__ Wf, _Float16* __restrict__ w1p,
    _Float16* __restrict__ w2p) {
  int i = blockIdx.x * 256 + threadIdx.x;     // grid covers 116736
  if (i < 192 * 96) {
    int g = i / 96, k = i - g * 96;
    float v = (k < 64) ? W_hh[g * 64 + k] : ((k < 70) ? W_ih[g * 6 + (k - 64)] : 0.f);
    Wf[i] = (_Float16)v;
  }
  int j = i - 192 * 96;
  if (j >= 0 && j < 32768) {
    int kt = j >> 11, ntl = (j >> 10) & 1, kf = (j >> 9) & 1;
    int lane = (j >> 3) & 63, e = j & 7;
    int q = lane >> 4, c = lane & 15;
    int row = kt * 32 + ntl * 16 + c;
    int h = kf * 32 + q * 8 + e;
    w1p[j] = (_Float16)w1[row * 64 + h];
  }
  int l = j - 32768;
  if (l >= 0 && l < 65536) {
    int kt = l >> 12, nt = (l >> 9) & 7;
    int lane = (l >> 3) & 63, e = l & 7;
    int q = lane >> 4, c = lane & 15;
    int row = nt * 16 + c;
    int k = kt * 32 + q * 8 + e;
    w2p[l] = (_Float16)w2[row * 512 + k];
  }
}

// ---------------------------------------------------------------- GRU via MFMA
// Block = 4 waves, 32 rows = TWO independent 16-row chains interleaved.
// Wave w owns gate-dims [16w,16w+16) of r,z,n for BOTH chains (weights
// shared). Each step issues 12 independent h-MFMAs (one dep level) + 2x
// gate VALU — the second chain fills the serial-latency bubbles of the
// first. Loop globally silent; 16-step hist chunks burst-dumped. Grid 100.
__global__ __launch_bounds__(256, 1) void gru_kernel(
    const float* __restrict__ x, const _Float16* __restrict__ Wf,
    const float* __restrict__ b_ih, const float* __restrict__ b_hh,
    _Float16* __restrict__ sx) {
  __shared__ __align__(16) _Float16 hist[16][32][72];  // 73.7 KB
  __shared__ __align__(16) _Float16 xs[Tdim][32][8];   // 64 KB
  const int tid = threadIdx.x;
  const int lane = tid & 63;
  const int w = tid >> 6;                     // wave id 0..3
  const int c = lane & 15;                    // MFMA col = row-in-chain
  const int q = lane >> 4;                    // quad

  // ---- preload x for this block's 32 rows, pre-converted to fp16
  for (int i = 0; i < 16; i++) {
    int idx = i * 256 + tid;                  // 0..4095 = (t, row)
    int t = idx >> 5, row = idx & 31;
    int nr = blockIdx.x * 32 + row;           // n = z*32 + b
    const float* p = x + (size_t)(nr & 31) * (Tdim * Zdim * Sdim)
                       + (size_t)t * (Zdim * Sdim) + (size_t)(nr >> 5) * Sdim;
    f16x8 v;
    v[0] = (_Float16)p[0]; v[1] = (_Float16)p[1]; v[2] = (_Float16)p[2];
    v[3] = (_Float16)p[3]; v[4] = (_Float16)p[4]; v[5] = (_Float16)p[5];
    v[6] = (_Float16)0.f;  v[7] = (_Float16)0.f;
    *(f16x8*)&xs[t][row][0] = v;
  }

  const int gr0 = w * 16;                     // r-gate tile base
  const int gz0 = 64 + w * 16;                // z-gate tile base
  const int gn0 = 128 + w * 16;               // n-gate tile base

  // A-frags: A[m=c][k=q*8+j] per 16-gate tile, K=96 fused [h|x|0]
  f16x8 Ar[3], Az[3], Anh[2], Ani;
#pragma unroll
  for (int kf = 0; kf < 3; kf++) {
    Ar[kf] = *(const f16x8*)(Wf + (size_t)(gr0 + c) * 96 + kf * 32 + q * 8);
    Az[kf] = *(const f16x8*)(Wf + (size_t)(gz0 + c) * 96 + kf * 32 + q * 8);
  }
  Anh[0] = *(const f16x8*)(Wf + (size_t)(gn0 + c) * 96 + q * 8);
  Anh[1] = *(const f16x8*)(Wf + (size_t)(gn0 + c) * 96 + 32 + q * 8);
  Ani    = *(const f16x8*)(Wf + (size_t)(gn0 + c) * 96 + 64 + q * 8);

  // biases in D-layout (gate-local m = q*4 + r)
  f32x4 Cr, Cz, Cnh, Cni;
  {
    f32x4 bir = *(const f32x4*)(b_ih + gr0 + q * 4);
    f32x4 bhr = *(const f32x4*)(b_hh + gr0 + q * 4);
    f32x4 biz = *(const f32x4*)(b_ih + gz0 + q * 4);
    f32x4 bhz = *(const f32x4*)(b_hh + gz0 + q * 4);
#pragma unroll
    for (int r = 0; r < 4; r++) { Cr[r] = bir[r] + bhr[r]; Cz[r] = biz[r] + bhz[r]; }
    Cnh = *(const f32x4*)(b_hh + gn0 + q * 4);
    Cni = *(const f32x4*)(b_ih + gn0 + q * 4);
  }

  __syncthreads();                            // xs ready

  f16x8 Bh0[2], Bh1[2];
  f32x4 hprev[2];
  f32x4 Dr_s[2], Dz_s[2], Dni_s[2];
  const f32x4 zero4 = {0.f, 0.f, 0.f, 0.f};
#pragma unroll
  for (int ch = 0; ch < 2; ch++) {
    Bh0[ch] = (f16x8){0, 0, 0, 0, 0, 0, 0, 0};
    Bh1[ch] = (f16x8){0, 0, 0, 0, 0, 0, 0, 0};
    hprev[ch] = zero4;
    // pipeline seeds for t=0: x-projection MFMAs
    f16x8 xv8 = *(const f16x8*)&xs[0][ch * 16 + c][0];
    f16x8 Bx;
#pragma unroll
    for (int j = 0; j < 8; j++) Bx[j] = (q == 0) ? xv8[j] : (_Float16)0.f;
    Dni_s[ch] = __builtin_amdgcn_mfma_f32_16x16x32_f16(Ani, Bx, Cni, 0, 0, 0);
    Dr_s[ch]  = __builtin_amdgcn_mfma_f32_16x16x32_f16(Ar[2], Bx, Cr, 0, 0, 0);
    Dz_s[ch]  = __builtin_amdgcn_mfma_f32_16x16x32_f16(Az[2], Bx, Cz, 0, 0, 0);
  }

#pragma unroll 1
  for (int tch = 0; tch < 8; tch++) {
#pragma unroll 1
    for (int tc = 0; tc < 16; tc++) {
      const int t = tch * 16 + tc;
      // ---- 12 INDEPENDENT h-MFMAs (one dep level, 2 chains)
      f32x4 dnh0[2], dr0[2], dz0[2], dnh1[2], dr1[2], dz1[2];
#pragma unroll
      for (int ch = 0; ch < 2; ch++) {
        dnh0[ch] = __builtin_amdgcn_mfma_f32_16x16x32_f16(Anh[0], Bh0[ch], Cnh, 0, 0, 0);
        dr0[ch]  = __builtin_amdgcn_mfma_f32_16x16x32_f16(Ar[0], Bh0[ch], Dr_s[ch], 0, 0, 0);
        dz0[ch]  = __builtin_amdgcn_mfma_f32_16x16x32_f16(Az[0], Bh0[ch], Dz_s[ch], 0, 0, 0);
        dnh1[ch] = __builtin_amdgcn_mfma_f32_16x16x32_f16(Anh[1], Bh1[ch], zero4, 0, 0, 0);
        dr1[ch]  = __builtin_amdgcn_mfma_f32_16x16x32_f16(Ar[1], Bh1[ch], zero4, 0, 0, 0);
        dz1[ch]  = __builtin_amdgcn_mfma_f32_16x16x32_f16(Az[1], Bh1[ch], zero4, 0, 0, 0);
      }
      // ---- gate math + hist write, both chains
#pragma unroll
      for (int ch = 0; ch < 2; ch++) {
        f16x4 pk;
#pragma unroll
        for (int r = 0; r < 4; r++) {
          float rr = sigmoidf_fast(dr0[ch][r] + dr1[ch][r]);
          float zg = sigmoidf_fast(dz0[ch][r] + dz1[ch][r]);
          float nn = tanhf_fast(Dni_s[ch][r] + rr * (dnh0[ch][r] + dnh1[ch][r]));
          float hnew = nn + zg * (hprev[ch][r] - nn);
          hprev[ch][r] = hnew;
          pk[r] = (_Float16)hnew;
        }
        *(f16x4*)&hist[tc][ch * 16 + c][w * 16 + q * 4] = pk;
      }
      // ---- pre-barrier: x-projection for t+1 (h-independent)
      if (t + 1 < Tdim) {
#pragma unroll
        for (int ch = 0; ch < 2; ch++) {
          f16x8 xv8 = *(const f16x8*)&xs[t + 1][ch * 16 + c][0];
          f16x8 Bx;
#pragma unroll
          for (int j = 0; j < 8; j++) Bx[j] = (q == 0) ? xv8[j] : (_Float16)0.f;
          Dni_s[ch] = __builtin_amdgcn_mfma_f32_16x16x32_f16(Ani, Bx, Cni, 0, 0, 0);
          Dr_s[ch]  = __builtin_amdgcn_mfma_f32_16x16x32_f16(Ar[2], Bx, Cr, 0, 0, 0);
          Dz_s[ch]  = __builtin_amdgcn_mfma_f32_16x16x32_f16(Az[2], Bx, Cz, 0, 0, 0);
        }
      }
      __syncthreads();                        // lgkm-only drain
#pragma unroll
      for (int ch = 0; ch < 2; ch++) {
        Bh0[ch] = *(const f16x8*)&hist[tc][ch * 16 + c][q * 8];
        Bh1[ch] = *(const f16x8*)&hist[tc][ch * 16 + c][32 + q * 8];
      }
    }
    // coalesced dump of the 16-step chunk; wave w handles rows 8w..8w+7
    {
      const int t0 = tch * 16;
#pragma unroll
      for (int rr2 = 0; rr2 < 8; rr2++) {
        const int row = w * 8 + rr2;
        const int nrow = blockIdx.x * 32 + row;
        _Float16* dst = sx + (size_t)nrow * Tdim * Hdim + (size_t)t0 * Hdim;
#pragma unroll
        for (int it = 0; it < 2; it++) {
          int idx = it * 64 + lane;           // 0..127
          int tcc = idx >> 3, hd8 = idx & 7;
          f16x8 vv = *(const f16x8*)&hist[tcc][row][hd8 * 8];
          *(f16x8*)(dst + tcc * 64 + hd8 * 8) = vv;  // lane-contiguous 1 KB/iter
        }
      }
      __syncthreads();                        // dump reads done before hist reuse
    }
  }
}

// ---------------------------------------------------------------- fused MLP
// R8-exact (measured 100.2 us): block = 4 waves / 256 rows; wave = 64 rows
// (4 groups of 16) so every LDS A-frag read feeds 4 MFMAs. Weights
// double-buffered; rep single-buffered (wave-private, in-order). b1 seeded
// into MFMA C. 40 KB LDS. (256,2): VGPR cap 128 > 120 used — NO spills;
// arg>=3 caps VGPRs at ~85 and spills acc2 catastrophically (R9).
__global__ __launch_bounds__(256, 2) void mlp_kernel(
    const _Float16* __restrict__ sx, const _Float16* __restrict__ w1p,
    const _Float16* __restrict__ w2p, const float* __restrict__ b1,
    const float* __restrict__ b2, const float* __restrict__ w3,
    const float* __restrict__ b3, float* __restrict__ out) {
  __shared__ __align__(16) _Float16 w1s[2][2048];      // 8 KB  [ntl][kf][lane][8]
  __shared__ __align__(16) _Float16 w2s[2][4096];      // 16 KB [nt][lane][8]
  __shared__ __align__(16) _Float16 rep[4][4][512];    // 16 KB [wave][g][lane*8]
  const int tid = threadIdx.x;
  const int lane = tid & 63;
  const int wave = tid >> 6;
  const int c = lane & 15;
  const int q = lane >> 4;
  const size_t m0 = ((size_t)blockIdx.x * 4 + wave) * 64;

  // activations (rows) as B-frags for the whole kernel: 4 groups of 16 rows
  f16x8 Bs[4][2];
#pragma unroll
  for (int g = 0; g < 4; g++)
#pragma unroll
    for (int kk = 0; kk < 2; kk++)
      Bs[g][kk] = *(const f16x8*)(sx + (m0 + g * 16 + c) * Hdim + kk * 32 + q * 8);

  f32x4 acc2[4][8];
#pragma unroll
  for (int g = 0; g < 4; g++)
#pragma unroll
    for (int nt = 0; nt < 8; nt++) acc2[g][nt] = (f32x4){0.f, 0.f, 0.f, 0.f};

  u32x4 r1, r2a, r2b;
  // stage kt=0 and commit before the loop
  {
    const u32x4* g1 = (const u32x4*)(w1p);
    const u32x4* g2 = (const u32x4*)(w2p);
    r1 = g1[tid];
    r2a = g2[tid];
    r2b = g2[256 + tid];
    ((u32x4*)&w1s[0][0])[tid] = r1;
    ((u32x4*)&w2s[0][0])[tid] = r2a;
    ((u32x4*)&w2s[0][0])[256 + tid] = r2b;
  }
  __syncthreads();

#pragma unroll 1
  for (int kt = 0; kt < 16; kt++) {
    const int buf = kt & 1;
    // issue loads for kt+1 (land during compute below)
    if (kt + 1 < 16) {
      const u32x4* g1 = (const u32x4*)(w1p + (size_t)(kt + 1) * 2048);
      const u32x4* g2 = (const u32x4*)(w2p + (size_t)(kt + 1) * 4096);
      r1 = g1[tid];
      r2a = g2[tid];
      r2b = g2[256 + tid];
    }

    // ---- layer1: two 16-wide f1 tiles; A-frags at lane*16B (conflict-free)
#pragma unroll
    for (int ntl = 0; ntl < 2; ntl++) {
      const int f1b = kt * 32 + ntl * 16;
      f16x8 A0 = *(const f16x8*)&w1s[buf][ntl * 1024 + lane * 8];
      f16x8 A1 = *(const f16x8*)&w1s[buf][ntl * 1024 + 512 + lane * 8];
      f32x4 bb = *(const f32x4*)(b1 + f1b + q * 4);
      // write target: B-frag-linear — lane_b = (2*ntl + q/2)*16 + c, half q&1
      const int roff = ((2 * ntl + (q >> 1)) * 16 + c) * 8 + (q & 1) * 4;
#pragma unroll
      for (int g = 0; g < 4; g++) {
        f32x4 cc = __builtin_amdgcn_mfma_f32_16x16x32_f16(A0, Bs[g][0], bb, 0, 0, 0);
        cc = __builtin_amdgcn_mfma_f32_16x16x32_f16(A1, Bs[g][1], cc, 0, 0, 0);
        f16x4 pk;
#pragma unroll
        for (int r = 0; r < 4; r++)
          pk[r] = (_Float16)(cc[r] > 0.f ? cc[r] : 0.f);
        *(f16x4*)&rep[wave][g][roff] = pk;
      }
    }
    // ---- a1 chunk back as B-frags: direct lane-linear b128 (conflict-free)
    f16x8 Ba[4];
#pragma unroll
    for (int g = 0; g < 4; g++)
      Ba[g] = *(const f16x8*)&rep[wave][g][lane * 8];
    // ---- layer2 partial; A2 frags at lane*16B, each feeds 4 MFMAs
#pragma unroll
    for (int nt = 0; nt < 8; nt++) {
      f16x8 A2 = *(const f16x8*)&w2s[buf][nt * 512 + lane * 8];
#pragma unroll
      for (int g = 0; g < 4; g++)
        acc2[g][nt] = __builtin_amdgcn_mfma_f32_16x16x32_f16(A2, Ba[g], acc2[g][nt], 0, 0, 0);
    }

    // ---- commit kt+1 regs -> other LDS buf, then barrier
    if (kt + 1 < 16) {
      ((u32x4*)&w1s[buf ^ 1][0])[tid] = r1;
      ((u32x4*)&w2s[buf ^ 1][0])[tid] = r2a;
      ((u32x4*)&w2s[buf ^ 1][0])[256 + tid] = r2b;
      __syncthreads();
    }
  }

  // ---- layer3: out[row] = sum relu(a2 + b2) * w3 + b3
  float part[4] = {0.f, 0.f, 0.f, 0.f};
#pragma unroll
  for (int nt = 0; nt < 8; nt++) {
    f32x4 bb = *(const f32x4*)(b2 + nt * 16 + q * 4);
    f32x4 ww = *(const f32x4*)(w3 + nt * 16 + q * 4);
#pragma unroll
    for (int g = 0; g < 4; g++) {
#pragma unroll
      for (int r = 0; r < 4; r++) {
        float v = acc2[g][nt][r] + bb[r];
        v = v > 0.f ? v : 0.f;
        part[g] = fmaf(v, ww[r], part[g]);
      }
    }
  }
#pragma unroll
  for (int g = 0; g < 4; g++) {
    part[g] += __shfl_xor(part[g], 16, 64);
    part[g] += __shfl_xor(part[g], 32, 64);
  }
  // lane (c,q) writes row q*16+c of this wave's 64 rows
  float pv = (q == 0) ? part[0] : (q == 1) ? part[1] : (q == 2) ? part[2] : part[3];
  out[m0 + q * 16 + c] = pv + b3[0];
}

// ----------------------------------------------------------------
extern "C" void kernel_launch(void* const* d_in, const int* in_sizes, int n_in,
                              void* d_out, int out_size, void* d_ws, size_t ws_size,
                              hipStream_t stream) {
  const float* x    = (const float*)d_in[0];
  const float* W_ih = (const float*)d_in[1];
  const float* W_hh = (const float*)d_in[2];
  const float* b_ih = (const float*)d_in[3];
  const float* b_hh = (const float*)d_in[4];
  const float* w1   = (const float*)d_in[5];
  const float* b1   = (const float*)d_in[6];
  const float* w2   = (const float*)d_in[7];
  const float* b2   = (const float*)d_in[8];
  const float* w3   = (const float*)d_in[9];
  const float* b3   = (const float*)d_in[10];
  float* out = (float*)d_out;

  char* ws = (char*)d_ws;
  _Float16* sxf = (_Float16*)ws;                          // 52,428,800 B
  _Float16* Wf  = (_Float16*)(ws + 52428800);             // 36,864 B
  _Float16* w1p = (_Float16*)(ws + 52428800 + 36864);     // 65,536 B
  _Float16* w2p = (_Float16*)(ws + 52428800 + 36864 + 65536); // 131,072 B

  hipLaunchKernelGGL(prep_kernel, dim3(456), dim3(256), 0, stream,
                     W_ih, W_hh, w1, w2, Wf, w1p, w2p);
  hipLaunchKernelGGL(gru_kernel, dim3(ZB / 32), dim3(256), 0, stream,
                     x, Wf, b_ih, b_hh, sxf);
  hipLaunchKernelGGL(mlp_kernel, dim3(Mrows / 256), dim3(256), 0, stream,
                     sxf, w1p, w2p, b1, b2, w3, b3, out);
}

// Round 11
// 257.893 us; speedup vs baseline: 2.2463x; 1.3604x over previous
//
#include <hip/hip_runtime.h>
#include <stdint.h>

#define Tdim 128
#define Zdim 100
#define Sdim 6
#define Hdim 64
#define ZB   3200           // Z*B
#define F1   512
#define F2   128
#define Mrows (ZB * Tdim)   // 409600

typedef _Float16 f16x8 __attribute__((ext_vector_type(8)));
typedef _Float16 f16x4 __attribute__((ext_vector_type(4)));
typedef float f32x4 __attribute__((ext_vector_type(4)));
typedef uint32_t u32x4 __attribute__((ext_vector_type(4)));

__device__ __forceinline__ float sigmoidf_fast(float x) {
  return 1.f / (1.f + __expf(-x));
}
__device__ __forceinline__ float tanhf_fast(float x) {
  return 1.f - 2.f / (__expf(2.f * x) + 1.f);
}

// ---------------------------------------------------------------- prep
// Wf[192][96] fp16: [W_hh | W_ih | 0] per gate (K=96 fused), for the GRU.
// w1p frag-linear: [kt][ntl][kfrag][lane][8].  32768 f16.
// w2p frag-linear: [kt][nt][lane][8].          65536 f16.
__global__ __launch_bounds__(256) void prep_kernel(
    const float* __restrict__ W_ih, const float* __restrict__ W_hh,
    const float* __restrict__ w1, const float* __restrict__ w2,
    _Float16* __restrict__ Wf, _Float16* __restrict__ w1p,
    _Float16* __restrict__ w2p) {
  int i = blockIdx.x * 256 + threadIdx.x;     // grid covers 116736
  if (i < 192 * 96) {
    int g = i / 96, k = i - g * 96;
    float v = (k < 64) ? W_hh[g * 64 + k] : ((k < 70) ? W_ih[g * 6 + (k - 64)] : 0.f);
    Wf[i] = (_Float16)v;
  }
  int j = i - 192 * 96;
  if (j >= 0 && j < 32768) {
    int kt = j >> 11, ntl = (j >> 10) & 1, kf = (j >> 9) & 1;
    int lane = (j >> 3) & 63, e = j & 7;
    int q = lane >> 4, c = lane & 15;
    int row = kt * 32 + ntl * 16 + c;
    int h = kf * 32 + q * 8 + e;
    w1p[j] = (_Float16)w1[row * 64 + h];
  }
  int l = j - 32768;
  if (l >= 0 && l < 65536) {
    int kt = l >> 12, nt = (l >> 9) & 7;
    int lane = (l >> 3) & 63, e = l & 7;
    int q = lane >> 4, c = lane & 15;
    int row = nt * 16 + c;
    int k = kt * 32 + q * 8 + e;
    w2p[l] = (_Float16)w2[row * 512 + k];
  }
}

// ---------------------------------------------------------------- GRU via MFMA
// R9-exact single-chain (best measured GRU): block = 4 waves, 16 rows;
// wave w owns gate-dims [16w,16w+16) of r,z,n. Independent h-MFMA partials,
// x-projection for t+1 pipelined pre-barrier, globally silent loop, burst
// dumps. Grid 200. (R10's 2-chain interleave was additive — reverted.)
__global__ __launch_bounds__(256, 1) void gru_kernel(
    const float* __restrict__ x, const _Float16* __restrict__ Wf,
    const float* __restrict__ b_ih, const float* __restrict__ b_hh,
    _Float16* __restrict__ sx) {
  __shared__ __align__(16) _Float16 hist[32][16][72];  // 72 KB
  __shared__ __align__(16) _Float16 xs[Tdim][16][8];   // 32 KB
  const int tid = threadIdx.x;
  const int lane = tid & 63;
  const int w = tid >> 6;                     // wave id 0..3
  const int c = lane & 15;                    // MFMA col = row index
  const int q = lane >> 4;                    // quad

  // ---- preload x for this block's 16 rows, pre-converted to fp16
  for (int i = 0; i < 8; i++) {
    int idx = i * 256 + tid;                  // 0..2047 = (t, row)
    int t = idx >> 4, row = idx & 15;
    int nr = blockIdx.x * 16 + row;           // n = z*32 + b
    const float* p = x + (size_t)(nr & 31) * (Tdim * Zdim * Sdim)
                       + (size_t)t * (Zdim * Sdim) + (size_t)(nr >> 5) * Sdim;
    f16x8 v;
    v[0] = (_Float16)p[0]; v[1] = (_Float16)p[1]; v[2] = (_Float16)p[2];
    v[3] = (_Float16)p[3]; v[4] = (_Float16)p[4]; v[5] = (_Float16)p[5];
    v[6] = (_Float16)0.f;  v[7] = (_Float16)0.f;
    *(f16x8*)&xs[t][row][0] = v;
  }

  const int gr0 = w * 16;                     // r-gate tile base
  const int gz0 = 64 + w * 16;                // z-gate tile base
  const int gn0 = 128 + w * 16;               // n-gate tile base

  // A-frags: A[m=c][k=q*8+j] per 16-gate tile, K=96 fused [h|x|0]
  f16x8 Ar[3], Az[3], Anh[2], Ani;
#pragma unroll
  for (int kf = 0; kf < 3; kf++) {
    Ar[kf] = *(const f16x8*)(Wf + (size_t)(gr0 + c) * 96 + kf * 32 + q * 8);
    Az[kf] = *(const f16x8*)(Wf + (size_t)(gz0 + c) * 96 + kf * 32 + q * 8);
  }
  Anh[0] = *(const f16x8*)(Wf + (size_t)(gn0 + c) * 96 + q * 8);
  Anh[1] = *(const f16x8*)(Wf + (size_t)(gn0 + c) * 96 + 32 + q * 8);
  Ani    = *(const f16x8*)(Wf + (size_t)(gn0 + c) * 96 + 64 + q * 8);

  // biases in D-layout (gate-local m = q*4 + r)
  f32x4 Cr, Cz, Cnh, Cni;
  {
    f32x4 bir = *(const f32x4*)(b_ih + gr0 + q * 4);
    f32x4 bhr = *(const f32x4*)(b_hh + gr0 + q * 4);
    f32x4 biz = *(const f32x4*)(b_ih + gz0 + q * 4);
    f32x4 bhz = *(const f32x4*)(b_hh + gz0 + q * 4);
#pragma unroll
    for (int r = 0; r < 4; r++) { Cr[r] = bir[r] + bhr[r]; Cz[r] = biz[r] + bhz[r]; }
    Cnh = *(const f32x4*)(b_hh + gn0 + q * 4);
    Cni = *(const f32x4*)(b_ih + gn0 + q * 4);
  }

  __syncthreads();                            // xs ready

  f16x8 Bh0 = {0, 0, 0, 0, 0, 0, 0, 0};
  f16x8 Bh1 = {0, 0, 0, 0, 0, 0, 0, 0};
  f32x4 hprev = {0.f, 0.f, 0.f, 0.f};
  const f32x4 zero4 = {0.f, 0.f, 0.f, 0.f};

  // ---- pipeline seeds for t=0: x-projection MFMAs
  f32x4 Dr_s, Dz_s, Dni_s;
  {
    f16x8 xv8 = *(const f16x8*)&xs[0][c][0];
    f16x8 Bx;
#pragma unroll
    for (int j = 0; j < 8; j++) Bx[j] = (q == 0) ? xv8[j] : (_Float16)0.f;
    Dni_s = __builtin_amdgcn_mfma_f32_16x16x32_f16(Ani, Bx, Cni, 0, 0, 0);
    Dr_s  = __builtin_amdgcn_mfma_f32_16x16x32_f16(Ar[2], Bx, Cr, 0, 0, 0);
    Dz_s  = __builtin_amdgcn_mfma_f32_16x16x32_f16(Az[2], Bx, Cz, 0, 0, 0);
  }

#pragma unroll 1
  for (int tch = 0; tch < 4; tch++) {
#pragma unroll 1
    for (int tc = 0; tc < 32; tc++) {
      const int t = tch * 32 + tc;
      // ---- h-dependent MFMAs: 6 INDEPENDENT partials, one dep level
      f32x4 Dnh0 = __builtin_amdgcn_mfma_f32_16x16x32_f16(Anh[0], Bh0, Cnh, 0, 0, 0);
      f32x4 Dr0  = __builtin_amdgcn_mfma_f32_16x16x32_f16(Ar[0], Bh0, Dr_s, 0, 0, 0);
      f32x4 Dz0  = __builtin_amdgcn_mfma_f32_16x16x32_f16(Az[0], Bh0, Dz_s, 0, 0, 0);
      f32x4 Dnh1 = __builtin_amdgcn_mfma_f32_16x16x32_f16(Anh[1], Bh1, zero4, 0, 0, 0);
      f32x4 Dr1  = __builtin_amdgcn_mfma_f32_16x16x32_f16(Ar[1], Bh1, zero4, 0, 0, 0);
      f32x4 Dz1  = __builtin_amdgcn_mfma_f32_16x16x32_f16(Az[1], Bh1, zero4, 0, 0, 0);

      f16x4 pk;
#pragma unroll
      for (int r = 0; r < 4; r++) {
        float rr = sigmoidf_fast(Dr0[r] + Dr1[r]);
        float zg = sigmoidf_fast(Dz0[r] + Dz1[r]);
        float nn = tanhf_fast(Dni_s[r] + rr * (Dnh0[r] + Dnh1[r]));
        float hnew = nn + zg * (hprev[r] - nn);
        hprev[r] = hnew;
        pk[r] = (_Float16)hnew;
      }
      *(f16x4*)&hist[tc][c][w * 16 + q * 4] = pk;

      // ---- pre-barrier: x-projection for t+1 (h-independent)
      if (t + 1 < Tdim) {
        f16x8 xv8 = *(const f16x8*)&xs[t + 1][c][0];
        f16x8 Bx;
#pragma unroll
        for (int j = 0; j < 8; j++) Bx[j] = (q == 0) ? xv8[j] : (_Float16)0.f;
        Dni_s = __builtin_amdgcn_mfma_f32_16x16x32_f16(Ani, Bx, Cni, 0, 0, 0);
        Dr_s  = __builtin_amdgcn_mfma_f32_16x16x32_f16(Ar[2], Bx, Cr, 0, 0, 0);
        Dz_s  = __builtin_amdgcn_mfma_f32_16x16x32_f16(Az[2], Bx, Cz, 0, 0, 0);
      }
      __syncthreads();                        // lgkm-only drain
      Bh0 = *(const f16x8*)&hist[tc][c][q * 8];
      Bh1 = *(const f16x8*)&hist[tc][c][32 + q * 8];
    }
    // coalesced dump of the 32-step chunk; wave w handles rows 4w..4w+3
    {
      const int t0 = tch * 32;
#pragma unroll
      for (int rr2 = 0; rr2 < 4; rr2++) {
        const int row = w * 4 + rr2;
        const int nrow = blockIdx.x * 16 + row;
        _Float16* dst = sx + (size_t)nrow * Tdim * Hdim + (size_t)t0 * Hdim;
#pragma unroll
        for (int it = 0; it < 4; it++) {
          int idx = it * 64 + lane;           // 0..255
          int tcc = idx >> 3, hd8 = idx & 7;
          f16x8 vv = *(const f16x8*)&hist[tcc][row][hd8 * 8];
          *(f16x8*)(dst + tcc * 64 + hd8 * 8) = vv;  // lane-contiguous 1 KB/iter
        }
      }
      __syncthreads();                        // dump reads done before hist reuse
    }
  }
}

// ---------------------------------------------------------------- fused MLP
// BARRIER-FREE: weight A-frags read directly from global (frag-linear, lane
// dwordx4 coalesced, L2-resident 192 KB shared by all 6400 waves). rep is
// wave-private LDS (in-order, lgkm only) — zero __syncthreads in the kernel,
// waves run free; TLP hides L2 latency. Wave = 64 rows (4 groups of 16).
// (256,2): VGPR cap 128 (>=3 spills acc2 — R9).
__global__ __launch_bounds__(256, 2) void mlp_kernel(
    const _Float16* __restrict__ sx, const _Float16* __restrict__ w1p,
    const _Float16* __restrict__ w2p, const float* __restrict__ b1,
    const float* __restrict__ b2, const float* __restrict__ w3,
    const float* __restrict__ b3, float* __restrict__ out) {
  __shared__ __align__(16) _Float16 rep[4][4][512];    // 16 KB [wave][g][lane*8]
  const int tid = threadIdx.x;
  const int lane = tid & 63;
  const int wave = tid >> 6;
  const int c = lane & 15;
  const int q = lane >> 4;
  const size_t m0 = ((size_t)blockIdx.x * 4 + wave) * 64;

  // activations (rows) as B-frags for the whole kernel: 4 groups of 16 rows
  f16x8 Bs[4][2];
#pragma unroll
  for (int g = 0; g < 4; g++)
#pragma unroll
    for (int kk = 0; kk < 2; kk++)
      Bs[g][kk] = *(const f16x8*)(sx + (m0 + g * 16 + c) * Hdim + kk * 32 + q * 8);

  f32x4 acc2[4][8];
#pragma unroll
  for (int g = 0; g < 4; g++)
#pragma unroll
    for (int nt = 0; nt < 8; nt++) acc2[g][nt] = (f32x4){0.f, 0.f, 0.f, 0.f};

#pragma unroll 2
  for (int kt = 0; kt < 16; kt++) {
    const _Float16* w1g = w1p + (size_t)kt * 2048 + lane * 8;
    const _Float16* w2g = w2p + (size_t)kt * 4096 + lane * 8;
    // ---- w1 A-frags straight from L2 (4 x dwordx4, coalesced)
    f16x8 A10 = *(const f16x8*)(w1g);
    f16x8 A11 = *(const f16x8*)(w1g + 512);
    f16x8 A12 = *(const f16x8*)(w1g + 1024);
    f16x8 A13 = *(const f16x8*)(w1g + 1536);

    // ---- layer1: two 16-wide f1 tiles, b1 seeded into C
#pragma unroll
    for (int ntl = 0; ntl < 2; ntl++) {
      const int f1b = kt * 32 + ntl * 16;
      f16x8 A0 = ntl ? A12 : A10;
      f16x8 A1 = ntl ? A13 : A11;
      f32x4 bb = *(const f32x4*)(b1 + f1b + q * 4);
      // write target: B-frag-linear — lane_b = (2*ntl + q/2)*16 + c, half q&1
      const int roff = ((2 * ntl + (q >> 1)) * 16 + c) * 8 + (q & 1) * 4;
#pragma unroll
      for (int g = 0; g < 4; g++) {
        f32x4 cc = __builtin_amdgcn_mfma_f32_16x16x32_f16(A0, Bs[g][0], bb, 0, 0, 0);
        cc = __builtin_amdgcn_mfma_f32_16x16x32_f16(A1, Bs[g][1], cc, 0, 0, 0);
        f16x4 pk;
#pragma unroll
        for (int r = 0; r < 4; r++)
          pk[r] = (_Float16)(cc[r] > 0.f ? cc[r] : 0.f);
        *(f16x4*)&rep[wave][g][roff] = pk;
      }
    }
    // ---- w2 A-frags from L2, issued before the rep read-back (overlap)
    f16x8 W2[8];
#pragma unroll
    for (int nt = 0; nt < 8; nt++)
      W2[nt] = *(const f16x8*)(w2g + nt * 512);
    // ---- a1 chunk back as B-frags: lane-linear b128 (wave-private, in-order)
    f16x8 Ba[4];
#pragma unroll
    for (int g = 0; g < 4; g++)
      Ba[g] = *(const f16x8*)&rep[wave][g][lane * 8];
    // ---- layer2 partial; each W2 frag feeds 4 MFMAs
#pragma unroll
    for (int nt = 0; nt < 8; nt++) {
#pragma unroll
      for (int g = 0; g < 4; g++)
        acc2[g][nt] = __builtin_amdgcn_mfma_f32_16x16x32_f16(W2[nt], Ba[g], acc2[g][nt], 0, 0, 0);
    }
  }

  // ---- layer3: out[row] = sum relu(a2 + b2) * w3 + b3
  float part[4] = {0.f, 0.f, 0.f, 0.f};
#pragma unroll
  for (int nt = 0; nt < 8; nt++) {
    f32x4 bb = *(const f32x4*)(b2 + nt * 16 + q * 4);
    f32x4 ww = *(const f32x4*)(w3 + nt * 16 + q * 4);
#pragma unroll
    for (int g = 0; g < 4; g++) {
#pragma unroll
      for (int r = 0; r < 4; r++) {
        float v = acc2[g][nt][r] + bb[r];
        v = v > 0.f ? v : 0.f;
        part[g] = fmaf(v, ww[r], part[g]);
      }
    }
  }
#pragma unroll
  for (int g = 0; g < 4; g++) {
    part[g] += __shfl_xor(part[g], 16, 64);
    part[g] += __shfl_xor(part[g], 32, 64);
  }
  // lane (c,q) writes row q*16+c of this wave's 64 rows
  float pv = (q == 0) ? part[0] : (q == 1) ? part[1] : (q == 2) ? part[2] : part[3];
  out[m0 + q * 16 + c] = pv + b3[0];
}

// ----------------------------------------------------------------
extern "C" void kernel_launch(void* const* d_in, const int* in_sizes, int n_in,
                              void* d_out, int out_size, void* d_ws, size_t ws_size,
                              hipStream_t stream) {
  const float* x    = (const float*)d_in[0];
  const float* W_ih = (const float*)d_in[1];
  const float* W_hh = (const float*)d_in[2];
  const float* b_ih = (const float*)d_in[3];
  const float* b_hh = (const float*)d_in[4];
  const float* w1   = (const float*)d_in[5];
  const float* b1   = (const float*)d_in[6];
  const float* w2   = (const float*)d_in[7];
  const float* b2   = (const float*)d_in[8];
  const float* w3   = (const float*)d_in[9];
  const float* b3   = (const float*)d_in[10];
  float* out = (float*)d_out;

  char* ws = (char*)d_ws;
  _Float16* sxf = (_Float16*)ws;                          // 52,428,800 B
  _Float16* Wf  = (_Float16*)(ws + 52428800);             // 36,864 B
  _Float16* w1p = (_Float16*)(ws + 52428800 + 36864);     // 65,536 B
  _Float16* w2p = (_Float16*)(ws + 52428800 + 36864 + 65536); // 131,072 B

  hipLaunchKernelGGL(prep_kernel, dim3(456), dim3(256), 0, stream,
                     W_ih, W_hh, w1, w2, Wf, w1p, w2p);
  hipLaunchKernelGGL(gru_kernel, dim3(ZB / 16), dim3(256), 0, stream,
                     x, Wf, b_ih, b_hh, sxf);
  hipLaunchKernelGGL(mlp_kernel, dim3(Mrows / 256), dim3(256), 0, stream,
                     sxf, w1p, w2p, b1, b2, w3, b3, out);
}